// Round 11
// baseline (191.803 us; speedup 1.0000x reference)
//
#include <hip/hip_runtime.h>
#include <cmath>

// ConvLSTM, two-phase.
//   Phase 1: xg = conv_same(x[:, ::-1], Wx). Direct global loads (LDS staging
//            SLOWER, R6). Depth-2 register pipeline over c with 4 NAMED
//            buffer sets (A,B,C,D) — spilled at __launch_bounds__(256,4)
//            (R9, 128-VGPR cap); this round runs (256,3) -> ~170 cap,
//            trading 4->3 blocks/CU for 2x pipeline depth.
//   Phase 2: 16 sequential F-split step kernels (R9-measured ~1.1 us/step).
//
// x:  (B=8, T=16, C=16, H=128, W=128) f32
// Wx: (KH=4, KW=2, C=16, O=8) HWIO     idx = kh*256 + kw*128 + c*8 + o
// Wh: (KH=4, KW=2, F=2, O=8)
// out:(B, T, F=2, H, W) f32
// ws: xg (64 MiB, layout [t][b][o][h][w]) + c-state (1 MiB)

constexpr int B_ = 8;
constexpr int T_ = 16;
constexpr int C_ = 16;
constexpr int F_ = 2;
constexpr int O_ = 8;
constexpr int H_ = 128;
constexpr int W_ = 128;
constexpr int HW_ = H_ * W_;
constexpr int KH_ = 4;
constexpr int KW_ = 2;
constexpr int PX_ = 4;

typedef float fv4 __attribute__((ext_vector_type(4)));

__device__ __forceinline__ float hsig(float z) {
    return fminf(fmaxf(0.2f * z + 0.5f, 0.0f), 1.0f);
}

__device__ __forceinline__ float ftanh(float x) {
    float e = __expf(2.0f * x);
    return fmaf(-2.0f, 1.0f / (e + 1.0f), 1.0f);
}

// load the 4 input rows (ih = r0-1 .. r0+2) of one channel plane
template<bool CHECK>
__device__ __forceinline__ void load4(
    const float* __restrict__ xc,   // channel base + ow4
    int r0m1, fv4 a[KH_])
{
    #pragma unroll
    for (int rr = 0; rr < KH_; ++rr) {
        int ih = r0m1 + rr;
        if (CHECK) {
            bool v = (unsigned)ih < (unsigned)H_;
            a[rr] = *reinterpret_cast<const fv4*>(xc + (v ? ih : 0) * W_);
            if (!v) a[rr] = (fv4)0.0f;
        } else {
            a[rr] = *reinterpret_cast<const fv4*>(xc + ih * W_);
        }
    }
}

// accumulate one channel: 4 kh-taps x 2 kw-taps x 8 outputs x 4 px
__device__ __forceinline__ void accum4(
    const float* __restrict__ wc,   // Wx + c*O_
    const fv4 a[KH_], float acc[PX_][O_], bool cval)
{
    #pragma unroll
    for (int kh = 0; kh < KH_; ++kh) {
        float x4 = __shfl_down(a[kh].x, 1, 64);   // lane q+1's x0 = px ow4+4
        x4 = cval ? x4 : 0.0f;                    // q=31 wrap masked
        const float* wp = wc + kh * (KW_ * C_ * O_);
        #pragma unroll
        for (int o = 0; o < O_; ++o) {
            float w0 = wp[o];              // kw = 0 (uniform -> SGPR)
            float w1 = wp[C_ * O_ + o];    // kw = 1
            acc[0][o] = fmaf(a[kh].x, w0, acc[0][o]);
            acc[1][o] = fmaf(a[kh].y, w0, acc[1][o]);
            acc[2][o] = fmaf(a[kh].z, w0, acc[2][o]);
            acc[3][o] = fmaf(a[kh].w, w0, acc[3][o]);
            acc[0][o] = fmaf(a[kh].y, w1, acc[0][o]);
            acc[1][o] = fmaf(a[kh].z, w1, acc[1][o]);
            acc[2][o] = fmaf(a[kh].w, w1, acc[2][o]);
            acc[3][o] = fmaf(x4,      w1, acc[3][o]);
        }
    }
}

// depth-2 software pipeline over channels, 4 named buffers, period 4
template<bool CHECK>
__device__ __forceinline__ void conv_pipe(
    const float* __restrict__ xb,   // image base + ow4
    const float* __restrict__ Wx,
    int r0m1, bool cval, float acc[PX_][O_])
{
    fv4 A[KH_], Bv[KH_], Cv[KH_], Dv[KH_];
    load4<CHECK>(xb,        r0m1, A);
    load4<CHECK>(xb + HW_,  r0m1, Bv);
    #pragma unroll 1
    for (int g = 0; g < 4; ++g) {
        int cc = g * 4;
        load4<CHECK>(xb + (cc + 2) * HW_, r0m1, Cv);
        accum4(Wx + cc * O_, A, acc, cval);
        load4<CHECK>(xb + (cc + 3) * HW_, r0m1, Dv);
        accum4(Wx + (cc + 1) * O_, Bv, acc, cval);
        if (cc + 4 < C_) load4<CHECK>(xb + (cc + 4) * HW_, r0m1, A);
        accum4(Wx + (cc + 2) * O_, Cv, acc, cval);
        if (cc + 5 < C_) load4<CHECK>(xb + (cc + 5) * HW_, r0m1, Bv);
        accum4(Wx + (cc + 3) * O_, Dv, acc, cval);
    }
}

// grid: 2048 blocks x 256 thr; block = 8-row slab of one (b,t) image;
// thread = 4 w-pixels, all 8 gate chans.
__global__ __launch_bounds__(256, 3) void xg_kernel(
    const float* __restrict__ x,
    const float* __restrict__ Wx,
    float* __restrict__ xg)
{
    // XCD-chunked swizzle (2048 % 8 == 0 -> bijective)
    int wid = (blockIdx.x & 7) * 256 + (blockIdx.x >> 3);

    int bt   = wid >> 4;             // 16 blocks per (b,t)
    int slab = wid & 15;

    int tid  = threadIdx.x;
    int oh_l = tid >> 5;             // 0..7 local row
    int q    = tid & 31;
    int ow4  = q << 2;

    int r0 = slab * 8 + oh_l;

    int b    = bt >> 4;
    int trev = bt & 15;
    int t    = 15 - trev;

    const float* xb = x + (size_t)bt * C_ * HW_ + ow4;
    bool cval = ow4 < (W_ - 4);

    float acc[PX_][O_];
    #pragma unroll
    for (int p = 0; p < PX_; ++p)
        #pragma unroll
        for (int o = 0; o < O_; ++o) acc[p][o] = 0.0f;

    // rows touched: r0-1 .. r0+2; interior slabs 1..14 are select-free
    if (slab >= 1 && slab <= 14) {
        conv_pipe<false>(xb, Wx, r0 - 1, cval, acc);
    } else {
        conv_pipe<true>(xb, Wx, r0 - 1, cval, acc);
    }

    float* dst = xg + (size_t)(t * B_ + b) * O_ * HW_ + r0 * W_ + ow4;
    #pragma unroll
    for (int o = 0; o < O_; ++o) {
        fv4 s;
        s.x = acc[0][o]; s.y = acc[1][o]; s.z = acc[2][o]; s.w = acc[3][o];
        __builtin_nontemporal_store(s, reinterpret_cast<fv4*>(dst + o * HW_));
    }
}

// ---------------- Phase 2: sequential LSTM step (F-split) ----------------
// grid: 1024 blocks (= B*H) x 256 thr. Block = one image row of one b.
// tid 0..127 -> f=0 for 128 pixels; tid 128..255 -> f=1 same pixels.
// f is wave-uniform -> weight loads stay scalar.
__global__ __launch_bounds__(256) void step_kernel(
    const float* __restrict__ xg,
    const float* __restrict__ Wh,
    float* __restrict__ out,
    float* __restrict__ cbuf,
    int t)
{
    int tid = threadIdx.x;
    int f   = tid >> 7;              // 0 or 1 (wave-uniform)
    int ow  = tid & 127;
    int oh  = blockIdx.x & 127;
    int b   = blockIdx.x >> 7;
    int pix = oh * W_ + ow;

    // gate accumulators start from xg_t (chans: i=f, f=2+f, g=4+f, o=6+f)
    const float* xgp = xg + ((size_t)(t * B_ + b) * O_ + f) * HW_ + pix;
    float a_i = __builtin_nontemporal_load(xgp);
    float a_f = __builtin_nontemporal_load(xgp + 2 * HW_);
    float a_g = __builtin_nontemporal_load(xgp + 4 * HW_);
    float a_o = __builtin_nontemporal_load(xgp + 6 * HW_);

    bool cv  = (ow + 1) < W_;
    int  co1 = cv ? 1 : 0;

    if (t > 0) {
        const float* hs = out + (size_t)(b * T_ + (t - 1)) * F_ * HW_;
        #pragma unroll
        for (int kh = 0; kh < KH_; ++kh) {
            int ih  = oh + kh - 1;
            bool rv = (unsigned)ih < (unsigned)H_;
            int ihc = rv ? ih : 0;
            const float* hrow = hs + ihc * W_ + ow;
            #pragma unroll
            for (int fin = 0; fin < F_; ++fin) {
                float h0 = hrow[fin * HW_];
                float h1 = hrow[fin * HW_ + co1];
                h0 = rv ? h0 : 0.0f;
                h1 = (rv && cv) ? h1 : 0.0f;
                // Wh idx = kh*32 + kw*16 + fin*8 + o; o = {f, 2+f, 4+f, 6+f}
                const float* wb = Wh + kh * (KW_ * F_ * O_) + fin * O_ + f;
                a_i = fmaf(h0, wb[0],  a_i);  a_i = fmaf(h1, wb[16], a_i);
                a_f = fmaf(h0, wb[2],  a_f);  a_f = fmaf(h1, wb[18], a_f);
                a_g = fmaf(h0, wb[4],  a_g);  a_g = fmaf(h1, wb[20], a_g);
                a_o = fmaf(h0, wb[6],  a_o);  a_o = fmaf(h1, wb[22], a_o);
            }
        }
    }

    float gi = hsig(a_i);
    float gf = hsig(a_f);
    float gg = ftanh(a_g);
    float go = hsig(a_o);

    size_t cidx = (size_t)b * F_ * HW_ + (size_t)f * HW_ + pix;
    float cp = (t > 0) ? cbuf[cidx] : 0.0f;
    float cn = gf * cp + gi * gg;
    cbuf[cidx] = cn;

    out[(size_t)(b * T_ + t) * F_ * HW_ + (size_t)f * HW_ + pix] = go * ftanh(cn);
}

extern "C" void kernel_launch(void* const* d_in, const int* in_sizes, int n_in,
                              void* d_out, int out_size, void* d_ws, size_t ws_size,
                              hipStream_t stream) {
    const float* x  = (const float*)d_in[0];
    const float* Wx = (const float*)d_in[1];
    const float* Wh = (const float*)d_in[2];
    float* out  = (float*)d_out;

    float* xg   = (float*)d_ws;                                            // 64 MiB
    float* cbuf = (float*)((char*)d_ws + (size_t)64 * 1024 * 1024 + 1024); // 1 MiB

    int xg_blocks = (B_ * T_ * HW_ / PX_) / 256;   // 2048
    xg_kernel<<<xg_blocks, 256, 0, stream>>>(x, Wx, xg);

    int step_blocks = B_ * H_;                     // 1024
    for (int t = 0; t < T_; ++t) {
        step_kernel<<<step_blocks, 256, 0, stream>>>(xg, Wh, out, cbuf, t);
    }
}

// Round 12
// 132.156 us; speedup vs baseline: 1.4513x; 1.4513x over previous
//
#include <hip/hip_runtime.h>
#include <cmath>

// ConvLSTM, two-phase. Consolidated best-known:
//   Phase 1: xg = conv_same(x[:, ::-1], Wx). R8's depth-1 A/B register
//            pipeline at __launch_bounds__(256,4) — depth-2 failed 3x
//            (spill R7/R9, codegen R11). REGULAR stores (NT hint removed:
//            xg fits L3; NT evicted it and made the 16 step kernels read
//            cold — suspected cause of R10's 140 vs 83 expected).
//   Phase 2: 16 sequential F-split step kernels (R9, ~1.1 us/step),
//            REGULAR loads (NT hint removed, same reason).
//
// x:  (B=8, T=16, C=16, H=128, W=128) f32
// Wx: (KH=4, KW=2, C=16, O=8) HWIO     idx = kh*256 + kw*128 + c*8 + o
// Wh: (KH=4, KW=2, F=2, O=8)
// out:(B, T, F=2, H, W) f32
// ws: xg (64 MiB, layout [t][b][o][h][w]) + c-state (1 MiB)

constexpr int B_ = 8;
constexpr int T_ = 16;
constexpr int C_ = 16;
constexpr int F_ = 2;
constexpr int O_ = 8;
constexpr int H_ = 128;
constexpr int W_ = 128;
constexpr int HW_ = H_ * W_;
constexpr int KH_ = 4;
constexpr int KW_ = 2;
constexpr int PX_ = 4;

typedef float fv4 __attribute__((ext_vector_type(4)));

__device__ __forceinline__ float hsig(float z) {
    return fminf(fmaxf(0.2f * z + 0.5f, 0.0f), 1.0f);
}

__device__ __forceinline__ float ftanh(float x) {
    float e = __expf(2.0f * x);
    return fmaf(-2.0f, 1.0f / (e + 1.0f), 1.0f);
}

// load the 4 input rows (ih = r0-1 .. r0+2) of one channel plane
template<bool CHECK>
__device__ __forceinline__ void load4(
    const float* __restrict__ xc,   // channel base + ow4
    int r0m1, fv4 a[KH_])
{
    #pragma unroll
    for (int rr = 0; rr < KH_; ++rr) {
        int ih = r0m1 + rr;
        if (CHECK) {
            bool v = (unsigned)ih < (unsigned)H_;
            a[rr] = *reinterpret_cast<const fv4*>(xc + (v ? ih : 0) * W_);
            if (!v) a[rr] = (fv4)0.0f;
        } else {
            a[rr] = *reinterpret_cast<const fv4*>(xc + ih * W_);
        }
    }
}

// accumulate one channel: 4 kh-taps x 2 kw-taps x 8 outputs x 4 px
__device__ __forceinline__ void accum4(
    const float* __restrict__ wc,   // Wx + c*O_
    const fv4 a[KH_], float acc[PX_][O_], bool cval)
{
    #pragma unroll
    for (int kh = 0; kh < KH_; ++kh) {
        float x4 = __shfl_down(a[kh].x, 1, 64);   // lane q+1's x0 = px ow4+4
        x4 = cval ? x4 : 0.0f;                    // q=31 wrap masked
        const float* wp = wc + kh * (KW_ * C_ * O_);
        #pragma unroll
        for (int o = 0; o < O_; ++o) {
            float w0 = wp[o];              // kw = 0 (uniform -> SGPR)
            float w1 = wp[C_ * O_ + o];    // kw = 1
            acc[0][o] = fmaf(a[kh].x, w0, acc[0][o]);
            acc[1][o] = fmaf(a[kh].y, w0, acc[1][o]);
            acc[2][o] = fmaf(a[kh].z, w0, acc[2][o]);
            acc[3][o] = fmaf(a[kh].w, w0, acc[3][o]);
            acc[0][o] = fmaf(a[kh].y, w1, acc[0][o]);
            acc[1][o] = fmaf(a[kh].z, w1, acc[1][o]);
            acc[2][o] = fmaf(a[kh].w, w1, acc[2][o]);
            acc[3][o] = fmaf(x4,      w1, acc[3][o]);
        }
    }
}

// depth-1 software pipeline over channels, 2 named buffers (A/B)
template<bool CHECK>
__device__ __forceinline__ void conv_pipe(
    const float* __restrict__ xb,   // image base + ow4
    const float* __restrict__ Wx,
    int r0m1, bool cval, float acc[PX_][O_])
{
    fv4 A[KH_], Bv[KH_];
    load4<CHECK>(xb, r0m1, A);
    #pragma unroll 1
    for (int cc = 0; cc < C_ - 2; cc += 2) {
        load4<CHECK>(xb + (cc + 1) * HW_, r0m1, Bv);
        accum4(Wx + cc * O_, A, acc, cval);
        load4<CHECK>(xb + (cc + 2) * HW_, r0m1, A);
        accum4(Wx + (cc + 1) * O_, Bv, acc, cval);
    }
    load4<CHECK>(xb + (C_ - 1) * HW_, r0m1, Bv);
    accum4(Wx + (C_ - 2) * O_, A, acc, cval);
    accum4(Wx + (C_ - 1) * O_, Bv, acc, cval);
}

// grid: 2048 blocks x 256 thr; block = 8-row slab of one (b,t) image;
// thread = 4 w-pixels, all 8 gate chans.
__global__ __launch_bounds__(256, 4) void xg_kernel(
    const float* __restrict__ x,
    const float* __restrict__ Wx,
    float* __restrict__ xg)
{
    // XCD-chunked swizzle (2048 % 8 == 0 -> bijective)
    int wid = (blockIdx.x & 7) * 256 + (blockIdx.x >> 3);

    int bt   = wid >> 4;             // 16 blocks per (b,t)
    int slab = wid & 15;

    int tid  = threadIdx.x;
    int oh_l = tid >> 5;             // 0..7 local row
    int q    = tid & 31;
    int ow4  = q << 2;

    int r0 = slab * 8 + oh_l;

    int b    = bt >> 4;
    int trev = bt & 15;
    int t    = 15 - trev;

    const float* xb = x + (size_t)bt * C_ * HW_ + ow4;
    bool cval = ow4 < (W_ - 4);

    float acc[PX_][O_];
    #pragma unroll
    for (int p = 0; p < PX_; ++p)
        #pragma unroll
        for (int o = 0; o < O_; ++o) acc[p][o] = 0.0f;

    // rows touched: r0-1 .. r0+2; interior slabs 1..14 are select-free
    if (slab >= 1 && slab <= 14) {
        conv_pipe<false>(xb, Wx, r0 - 1, cval, acc);
    } else {
        conv_pipe<true>(xb, Wx, r0 - 1, cval, acc);
    }

    float* dst = xg + (size_t)(t * B_ + b) * O_ * HW_ + r0 * W_ + ow4;
    #pragma unroll
    for (int o = 0; o < O_; ++o) {
        fv4 s;
        s.x = acc[0][o]; s.y = acc[1][o]; s.z = acc[2][o]; s.w = acc[3][o];
        *reinterpret_cast<fv4*>(dst + o * HW_) = s;   // regular store: keep L2/L3
    }
}

// ---------------- Phase 2: sequential LSTM step (F-split) ----------------
// grid: 1024 blocks (= B*H) x 256 thr. Block = one image row of one b.
// tid 0..127 -> f=0 for 128 pixels; tid 128..255 -> f=1 same pixels.
// f is wave-uniform -> weight loads stay scalar.
__global__ __launch_bounds__(256) void step_kernel(
    const float* __restrict__ xg,
    const float* __restrict__ Wh,
    float* __restrict__ out,
    float* __restrict__ cbuf,
    int t)
{
    int tid = threadIdx.x;
    int f   = tid >> 7;              // 0 or 1 (wave-uniform)
    int ow  = tid & 127;
    int oh  = blockIdx.x & 127;
    int b   = blockIdx.x >> 7;
    int pix = oh * W_ + ow;

    // gate accumulators start from xg_t (chans: i=f, f=2+f, g=4+f, o=6+f)
    const float* xgp = xg + ((size_t)(t * B_ + b) * O_ + f) * HW_ + pix;
    float a_i = xgp[0];
    float a_f = xgp[2 * HW_];
    float a_g = xgp[4 * HW_];
    float a_o = xgp[6 * HW_];

    bool cv  = (ow + 1) < W_;
    int  co1 = cv ? 1 : 0;

    if (t > 0) {
        const float* hs = out + (size_t)(b * T_ + (t - 1)) * F_ * HW_;
        #pragma unroll
        for (int kh = 0; kh < KH_; ++kh) {
            int ih  = oh + kh - 1;
            bool rv = (unsigned)ih < (unsigned)H_;
            int ihc = rv ? ih : 0;
            const float* hrow = hs + ihc * W_ + ow;
            #pragma unroll
            for (int fin = 0; fin < F_; ++fin) {
                float h0 = hrow[fin * HW_];
                float h1 = hrow[fin * HW_ + co1];
                h0 = rv ? h0 : 0.0f;
                h1 = (rv && cv) ? h1 : 0.0f;
                // Wh idx = kh*32 + kw*16 + fin*8 + o; o = {f, 2+f, 4+f, 6+f}
                const float* wb = Wh + kh * (KW_ * F_ * O_) + fin * O_ + f;
                a_i = fmaf(h0, wb[0],  a_i);  a_i = fmaf(h1, wb[16], a_i);
                a_f = fmaf(h0, wb[2],  a_f);  a_f = fmaf(h1, wb[18], a_f);
                a_g = fmaf(h0, wb[4],  a_g);  a_g = fmaf(h1, wb[20], a_g);
                a_o = fmaf(h0, wb[6],  a_o);  a_o = fmaf(h1, wb[22], a_o);
            }
        }
    }

    float gi = hsig(a_i);
    float gf = hsig(a_f);
    float gg = ftanh(a_g);
    float go = hsig(a_o);

    size_t cidx = (size_t)b * F_ * HW_ + (size_t)f * HW_ + pix;
    float cp = (t > 0) ? cbuf[cidx] : 0.0f;
    float cn = gf * cp + gi * gg;
    cbuf[cidx] = cn;

    out[(size_t)(b * T_ + t) * F_ * HW_ + (size_t)f * HW_ + pix] = go * ftanh(cn);
}

extern "C" void kernel_launch(void* const* d_in, const int* in_sizes, int n_in,
                              void* d_out, int out_size, void* d_ws, size_t ws_size,
                              hipStream_t stream) {
    const float* x  = (const float*)d_in[0];
    const float* Wx = (const float*)d_in[1];
    const float* Wh = (const float*)d_in[2];
    float* out  = (float*)d_out;

    float* xg   = (float*)d_ws;                                            // 64 MiB
    float* cbuf = (float*)((char*)d_ws + (size_t)64 * 1024 * 1024 + 1024); // 1 MiB

    int xg_blocks = (B_ * T_ * HW_ / PX_) / 256;   // 2048
    xg_kernel<<<xg_blocks, 256, 0, stream>>>(x, Wx, xg);

    int step_blocks = B_ * H_;                     // 1024
    for (int t = 0; t < T_; ++t) {
        step_kernel<<<step_blocks, 256, 0, stream>>>(xg, Wh, out, cbuf, t);
    }
}